// Round 10
// baseline (13736.929 us; speedup 1.0000x reference)
//
#include <hip/hip_runtime.h>
#include <math.h>

#define Bc 16
#define Tc 2048
#define Dc 512
#define Hc 1024
#define Rc 16

// ---------------------------------------------------------------------------
// GEMM: out[M,1024] = X[M,512] @ W[512,1024], M = 32768.
// ---------------------------------------------------------------------------
__global__ __launch_bounds__(256) void gemm_xw(const float* __restrict__ X,
                                               const float* __restrict__ W,
                                               float* __restrict__ out)
{
    __shared__ float As[16][128];
    __shared__ float Bs[16][64];
    const int tid = threadIdx.x;
    const int m0 = blockIdx.x * 128;
    const int n0 = blockIdx.y * 64;
    const int tx = tid & 15, ty = tid >> 4;
    const int am = tid >> 2, ak = (tid & 3) * 4;
    const int bk = tid >> 4, bn = (tid & 15) * 4;
    float acc[8][4] = {};
    for (int k0 = 0; k0 < 512; k0 += 16) {
        if (k0) __syncthreads();
        float4 a0 = *(const float4*)&X[(size_t)(m0 + am) * 512 + k0 + ak];
        float4 a1 = *(const float4*)&X[(size_t)(m0 + am + 64) * 512 + k0 + ak];
        float4 bv = *(const float4*)&W[(size_t)(k0 + bk) * 1024 + n0 + bn];
        As[ak + 0][am] = a0.x; As[ak + 1][am] = a0.y;
        As[ak + 2][am] = a0.z; As[ak + 3][am] = a0.w;
        As[ak + 0][am + 64] = a1.x; As[ak + 1][am + 64] = a1.y;
        As[ak + 2][am + 64] = a1.z; As[ak + 3][am + 64] = a1.w;
        *(float4*)&Bs[bk][bn] = bv;
        __syncthreads();
        #pragma unroll
        for (int kk = 0; kk < 16; ++kk) {
            float4 x0 = *(const float4*)&As[kk][ty * 8];
            float4 x1 = *(const float4*)&As[kk][ty * 8 + 4];
            float4 y  = *(const float4*)&Bs[kk][tx * 4];
            float a[8] = {x0.x, x0.y, x0.z, x0.w, x1.x, x1.y, x1.z, x1.w};
            float bb[4] = {y.x, y.y, y.z, y.w};
            #pragma unroll
            for (int i = 0; i < 8; ++i)
                #pragma unroll
                for (int j = 0; j < 4; ++j)
                    acc[i][j] += a[i] * bb[j];
        }
    }
    #pragma unroll
    for (int i = 0; i < 8; ++i) {
        float4 r;
        r.x = acc[i][0]; r.y = acc[i][1]; r.z = acc[i][2]; r.w = acc[i][3];
        *(float4*)&out[(size_t)(m0 + ty * 8 + i) * 1024 + n0 + tx * 4] = r;
    }
}

// ---------------------------------------------------------------------------
// q, k, lambda projections.
// ---------------------------------------------------------------------------
__global__ __launch_bounds__(256) void qkl_kernel(const float* __restrict__ X,
    const float* __restrict__ Wq, const float* __restrict__ Wk,
    const float* __restrict__ Wd, const float* __restrict__ bd,
    float* __restrict__ q, float* __restrict__ k, float* __restrict__ lam)
{
    __shared__ float xs[8 * 512];
    const int tid = threadIdx.x;
    const size_t row0 = (size_t)blockIdx.x * 8;
    #pragma unroll
    for (int c = 0; c < 4; ++c) {
        int f = (c * 256 + tid) * 4;
        *(float4*)&xs[f] = *(const float4*)&X[row0 * 512 + f];
    }
    __syncthreads();
    for (int t = tid; t < 264; t += 256) {
        int r = t / 33, c = t - r * 33;
        const float* xr = &xs[r * 512];
        const float* Wp; int ldw;
        if (c < 16)      { Wp = Wq + c;        ldw = 16; }
        else if (c < 32) { Wp = Wk + (c - 16); ldw = 16; }
        else             { Wp = Wd;            ldw = 1;  }
        float s = 0.f;
        for (int kk = 0; kk < 512; ++kk) s += xr[kk] * Wp[(size_t)kk * ldw];
        if (c < 16)      q[(row0 + r) * 16 + c] = s;
        else if (c < 32) k[(row0 + r) * 16 + (c - 16)] = s;
        else             lam[row0 + r] = 1.f / (1.f + expf(-(s + bd[0])));
    }
}

// ---------------------------------------------------------------------------
// Fused recurrence, R10 = R8-proven exchange + three safe deltas:
//  (1) DUAL-STORE publish: sc0 (fresh line in local XCD L2 for same-XCD
//      fast polls) THEN sc0 sc1 (coherence point -> escalated consumers
//      always make progress). Consumer: R8 per-thread fast/slow select
//      with bounded (256) sticky escalation. Liveness unconditional.
//  (2) One barrier/step: each wave owns 8 cols x 2 batches over ALL 1024 k
//      (128 weight VGPRs, static idx); 17-shfl reduce-scatter butterfly
//      finishes outputs in-wave; wave stores its own outputs immediately.
//      hs + pre_lds double-buffered so waves may run one step skewed.
//  (3) stride-17 LDS windows: stage writes & matvec reads exactly 2-way.
// ---------------------------------------------------------------------------
__global__ __launch_bounds__(256, 1) void rec_fused(
    const float* __restrict__ Wh, const float* __restrict__ qg,
    const float* __restrict__ kg, const float* __restrict__ vg,
    const float* __restrict__ lamg, const float* __restrict__ bias,
    float* __restrict__ out0, float* __restrict__ hfin,
    float* __restrict__ Ffin, float* __restrict__ hbuf,
    int* __restrict__ xcc_tab)
{
    __shared__ float hs[2][2 * 1088];  // [buf][b*1088 + (k>>4)*17 + (k&15)]
    __shared__ float pre_lds[2][64];   // [buf][bb*32 + ci]
    __shared__ float F_lds[64][17];    // fast-weight state, pad 17

    const int tid = threadIdx.x;
    const int bid = blockIdx.x;
    const int g = bid & 7, sl = bid >> 3;
    const int c0 = sl * 32;
    const int lane = tid & 63;
    const int wv = tid >> 6;

    // ---- publish my XCD id (value xcc+1; table memset to 0xFF each launch)
    const int my_xcc = __builtin_amdgcn_s_getreg(63508) & 0xF; // hwreg XCC_ID
    if (tid == 0) {
        int val = my_xcc + 1;
        int* tp = xcc_tab + bid;
        asm volatile("global_store_dword %0, %1, off sc0 sc1"
                     :: "v"(tp), "v"(val) : "memory");
    }

    // ---- weights: lane covers k = lane*16..+15, cols c0+wv*8..+7 (static idx)
    float wr[128];
    #pragma unroll
    for (int i = 0; i < 16; ++i) {
        const float* wp = &Wh[(size_t)(lane * 16 + i) * 1024 + c0 + wv * 8];
        float4 wa = *(const float4*)wp;
        float4 wb = *(const float4*)(wp + 4);
        wr[i * 8 + 0] = wa.x; wr[i * 8 + 1] = wa.y;
        wr[i * 8 + 2] = wa.z; wr[i * 8 + 3] = wa.w;
        wr[i * 8 + 4] = wb.x; wr[i * 8 + 5] = wb.y;
        wr[i * 8 + 6] = wb.z; wr[i * 8 + 7] = wb.w;
    }

    // ---- stage geometry: thread owns 8 h values of one batch
    const int sb_ = tid >> 7;                 // batch-in-group 0/1
    const int f   = (tid & 127) * 8;          // col offset 0..1016
    const int physb = (f >> 4) * 17 + (f & 15);

    // ---- scope detect for MY window's producer (R8-proven, + escalation)
    int fastf;
    {
        const int prod_bid = (f >> 5) * 8 + g;
        const int* tp = xcc_tab + prod_bid;
        int tv;
        for (;;) {
            asm volatile("global_load_dword %0, %1, off sc0 sc1\n\t"
                         "s_waitcnt vmcnt(0)"
                         : "=&v"(tv) : "v"(tp) : "memory");
            if (tv != -1) break;
        }
        fastf = ((tv - 1) == my_xcc) ? 1 : 0;
    }

    // ---- scan roles (wave3) ----
    const int j64 = tid & 63;
    const int sb = j64 >> 5, sci = j64 & 31;
    const int sbg = g * 2 + sb;
    const bool isScan = (tid >= 192);

    float bias_r = 0.f, plam = 0.f, pv = 0.f, pxw = 0.f;
    float4 pq[4], pk4[4];
    if (isScan) {
        bias_r = bias[c0 + sci];
        #pragma unroll
        for (int r = 0; r < 16; ++r) F_lds[j64][r] = 0.f;
        const size_t row = (size_t)sbg * Tc;            // t = 0 inputs
        plam = lamg[row];
        pv   = vg[row * Hc + c0 + sci];
        pxw  = out0[row * Hc + c0 + sci];
        const float* qp  = qg + row * 16;
        const float* kpp = kg + row * 16;
        #pragma unroll
        for (int r4 = 0; r4 < 4; ++r4) {
            pq[r4]  = *(const float4*)(qp + r4 * 4);
            pk4[r4] = *(const float4*)(kpp + r4 * 4);
        }
    }

    const bool hb5 = (lane & 32) != 0;
    const bool hb4 = (lane & 16) != 0;
    const bool hb3 = (lane & 8)  != 0;
    const bool hb2 = (lane & 4)  != 0;

    for (int t = 0; t < Tc; ++t) {
        const int buf = t & 1;
        float* h_rd = hbuf + (t & 1) * (16 * 1024) + g * 2048;
        float* h_wr = hbuf + ((t + 1) & 1) * (16 * 1024) + g * 2048;
        const float off_r = ((t >> 1) & 1) ? 4.0f : 0.0f;
        const float off_w = (((t + 1) >> 1) & 1) ? 4.0f : 0.0f;

        // ---- wave3: fast-weight scan (hidden under the poll) ----
        if (isScan) {
            float rd = 0.f;
            #pragma unroll
            for (int r4 = 0; r4 < 4; ++r4) {
                float f0 = F_lds[j64][r4 * 4 + 0];
                float f1 = F_lds[j64][r4 * 4 + 1];
                float f2 = F_lds[j64][r4 * 4 + 2];
                float f3 = F_lds[j64][r4 * 4 + 3];
                f0 = plam * f0 + pv * pk4[r4].x; rd += f0 * pq[r4].x;
                f1 = plam * f1 + pv * pk4[r4].y; rd += f1 * pq[r4].y;
                f2 = plam * f2 + pv * pk4[r4].z; rd += f2 * pq[r4].z;
                f3 = plam * f3 + pv * pk4[r4].w; rd += f3 * pq[r4].w;
                F_lds[j64][r4 * 4 + 0] = f0;
                F_lds[j64][r4 * 4 + 1] = f1;
                F_lds[j64][r4 * 4 + 2] = f2;
                F_lds[j64][r4 * 4 + 3] = f3;
            }
            pre_lds[buf][j64] = pxw + rd + bias_r;
            if (t == Tc - 1) {
                #pragma unroll
                for (int r = 0; r < 16; ++r)
                    Ffin[((size_t)sbg * Hc + c0 + sci) * 16 + r] = F_lds[j64][r];
            } else {
                const size_t row = (size_t)sbg * Tc + (t + 1);
                plam = lamg[row];
                pv   = vg[row * Hc + c0 + sci];
                pxw  = out0[row * Hc + c0 + sci];
                const float* qp  = qg + row * 16;
                const float* kpp = kg + row * 16;
                #pragma unroll
                for (int r4 = 0; r4 < 4; ++r4) {
                    pq[r4]  = *(const float4*)(qp + r4 * 4);
                    pk4[r4] = *(const float4*)(kpp + r4 * 4);
                }
            }
        }

        // ---- poll own 8-value window, stage into hs[buf] ----
        {
            float* sp = &hs[buf][sb_ * 1088 + physb];
            if (t > 0) {
                const float lo = off_r - 1.5f, hi = off_r + 1.5f;
                const float* p0 = h_rd + sb_ * 1024 + f;
                const float* p1 = p0 + 4;
                float4 r0, r1;
                int tries = 0;
                for (;;) {
                    if (fastf) {
                        asm volatile(
                            "global_load_dwordx4 %0, %2, off sc0\n\t"
                            "global_load_dwordx4 %1, %3, off sc0\n\t"
                            "s_waitcnt vmcnt(0)"
                            : "=&v"(r0), "=&v"(r1)
                            : "v"(p0), "v"(p1) : "memory");
                    } else {
                        asm volatile(
                            "global_load_dwordx4 %0, %2, off sc0 sc1\n\t"
                            "global_load_dwordx4 %1, %3, off sc0 sc1\n\t"
                            "s_waitcnt vmcnt(0)"
                            : "=&v"(r0), "=&v"(r1)
                            : "v"(p0), "v"(p1) : "memory");
                    }
                    bool ok = r0.x > lo && r0.x < hi && r0.y > lo && r0.y < hi
                           && r0.z > lo && r0.z < hi && r0.w > lo && r0.w < hi
                           && r1.x > lo && r1.x < hi && r1.y > lo && r1.y < hi
                           && r1.z > lo && r1.z < hi && r1.w > lo && r1.w < hi;
                    if (ok) break;
                    if (fastf && ++tries > 256) fastf = 0;  // sticky escalation
                }
                r0.x -= off_r; r0.y -= off_r; r0.z -= off_r; r0.w -= off_r;
                r1.x -= off_r; r1.y -= off_r; r1.z -= off_r; r1.w -= off_r;
                *(float4*)(sp)     = r0;
                *(float4*)(sp + 4) = r1;
            } else {
                float4 z = {0.f, 0.f, 0.f, 0.f};
                *(float4*)(sp)     = z;
                *(float4*)(sp + 4) = z;
            }
        }
        __syncthreads();                       // hs[buf] + pre_lds[buf] ready

        // ---- matvec: 8 b128 LDS reads, 256 FMAs per thread ----
        float acc[16];
        #pragma unroll
        for (int z = 0; z < 16; ++z) acc[z] = 0.f;
        #pragma unroll
        for (int bb = 0; bb < 2; ++bb) {
            const float* hb = &hs[buf][bb * 1088 + lane * 17];
            #pragma unroll
            for (int e = 0; e < 4; ++e) {
                float4 h4 = *(const float4*)(hb + e * 4);
                #pragma unroll
                for (int cc = 0; cc < 8; ++cc)
                    acc[cc * 2 + bb] += h4.x * wr[(e * 4 + 0) * 8 + cc]
                                      + h4.y * wr[(e * 4 + 1) * 8 + cc]
                                      + h4.z * wr[(e * 4 + 2) * 8 + cc]
                                      + h4.w * wr[(e * 4 + 3) * 8 + cc];
            }
        }

        // ---- 17-shfl reduce-scatter butterfly (all indices static) ----
        float s8[8];
        #pragma unroll
        for (int z = 0; z < 8; ++z) {
            float keep = hb5 ? acc[8 + z] : acc[z];
            float send = hb5 ? acc[z] : acc[8 + z];
            s8[z] = keep + __shfl_xor(send, 32);
        }
        float s4[4];
        #pragma unroll
        for (int z = 0; z < 4; ++z) {
            float keep = hb4 ? s8[4 + z] : s8[z];
            float send = hb4 ? s8[z] : s8[4 + z];
            s4[z] = keep + __shfl_xor(send, 16);
        }
        float s2[2];
        #pragma unroll
        for (int z = 0; z < 2; ++z) {
            float keep = hb3 ? s4[2 + z] : s4[z];
            float send = hb3 ? s4[z] : s4[2 + z];
            s2[z] = keep + __shfl_xor(send, 8);
        }
        float v1k = (hb2 ? s2[1] : s2[0]) + __shfl_xor(hb2 ? s2[0] : s2[1], 4);
        v1k += __shfl_xor(v1k, 2);
        v1k += __shfl_xor(v1k, 1);
        // lane (z*4 + r) now holds total for z = (b5 b4 b3 b2)

        // ---- per-wave finish: tanh + DUAL publish + out store ----
        if ((lane & 3) == 0) {
            const int z  = lane >> 2;          // 0..15
            const int cc = z >> 1, bb = z & 1;
            const int ci = wv * 8 + cc;
            const int bg2 = g * 2 + bb;
            float tot = v1k + pre_lds[buf][bb * 32 + ci];
            float hv = tanhf(tot);
            float sv = hv + off_w;
            float* hp = h_wr + bb * 1024 + c0 + ci;
            asm volatile("global_store_dword %0, %1, off sc0"
                         :: "v"(hp), "v"(sv) : "memory");
            asm volatile("global_store_dword %0, %1, off sc0 sc1"
                         :: "v"(hp), "v"(sv) : "memory");
            size_t oidx = ((size_t)bg2 * Tc + t) * Hc + c0 + ci;
            out0[oidx] = hv;
            if (t == Tc - 1) hfin[(size_t)bg2 * Hc + c0 + ci] = hv;
        }
    }
}

// ---------------------------------------------------------------------------
extern "C" void kernel_launch(void* const* d_in, const int* in_sizes, int n_in,
                              void* d_out, int out_size, void* d_ws, size_t ws_size,
                              hipStream_t stream)
{
    const float* x    = (const float*)d_in[0];
    const float* Wx   = (const float*)d_in[1];
    const float* Wh   = (const float*)d_in[2];
    const float* Wq   = (const float*)d_in[3];
    const float* Wk   = (const float*)d_in[4];
    const float* Wv   = (const float*)d_in[5];
    const float* Wd   = (const float*)d_in[6];
    const float* bias = (const float*)d_in[7];
    const float* bd   = (const float*)d_in[8];

    float* out0 = (float*)d_out;                    // (B,T,H): xw, then h
    float* hfin = out0 + (size_t)Bc * Tc * Hc;      // (B,H)
    float* Ffin = hfin + (size_t)Bc * Hc;           // (B,H,R)

    float* wsf  = (float*)d_ws;
    float* v    = wsf;                               // B*T*H
    float* q    = v + (size_t)Bc * Tc * Hc;          // B*T*R
    float* k    = q + (size_t)Bc * Tc * Rc;          // B*T*R
    float* lam  = k + (size_t)Bc * Tc * Rc;          // B*T
    float* hbuf = lam + (size_t)Bc * Tc;             // 2 * B*H ping-pong
    int*   xcc  = (int*)(hbuf + 2 * (size_t)Bc * Hc);// 256 entries

    // 0x7F7F7F7F == 3.39e38f: invalid under both offsets -> poll-safe init.
    hipMemsetAsync(hbuf, 0x7F, 2 * (size_t)Bc * Hc * sizeof(float), stream);
    hipMemsetAsync(xcc, 0xFF, 256 * sizeof(int), stream);

    dim3 gg(256, 16);
    gemm_xw<<<gg, 256, 0, stream>>>(x, Wx, out0);   // xw -> out0
    gemm_xw<<<gg, 256, 0, stream>>>(x, Wv, v);      // v  -> ws
    qkl_kernel<<<4096, 256, 0, stream>>>(x, Wq, Wk, Wd, bd, q, k, lam);
    rec_fused<<<256, 256, 0, stream>>>(Wh, q, k, v, lam, bias,
                                       out0, hfin, Ffin, hbuf, xcc);
}

// Round 11
// 7535.731 us; speedup vs baseline: 1.8229x; 1.8229x over previous
//
#include <hip/hip_runtime.h>
#include <math.h>

#define Bc 16
#define Tc 2048
#define Dc 512
#define Hc 1024
#define Rc 16

// ---------------------------------------------------------------------------
// Fused projection GEMM: computes BOTH xw = X@Wx and v = X@Wv in one
// dispatch (blockIdx.z selects). BM=128, BN=128, BK=16, 256 threads,
// 8x8 micro-tile per thread -> 2x arithmetic intensity vs the R8 kernel.
// ---------------------------------------------------------------------------
__global__ __launch_bounds__(256) void gemm_fused(const float* __restrict__ X,
                                                  const float* __restrict__ Wx,
                                                  const float* __restrict__ Wv,
                                                  float* __restrict__ out0,
                                                  float* __restrict__ vout)
{
    __shared__ float As[16][128];
    __shared__ float Bs[16][128];
    const float* W = blockIdx.z ? Wv : Wx;
    float* out     = blockIdx.z ? vout : out0;
    const int tid = threadIdx.x;
    const int m0 = blockIdx.x * 128;
    const int n0 = blockIdx.y * 128;
    const int tx = tid & 15, ty = tid >> 4;
    const int ar = tid >> 1, ak = (tid & 1) * 8;    // A: row ar, k ak..+7
    const int br = tid >> 4, bn = (tid & 15) * 8;   // B: k-row br, col bn..+7
    float acc[8][8] = {};
    for (int k0 = 0; k0 < 512; k0 += 16) {
        if (k0) __syncthreads();
        float4 a0 = *(const float4*)&X[(size_t)(m0 + ar) * 512 + k0 + ak];
        float4 a1 = *(const float4*)&X[(size_t)(m0 + ar) * 512 + k0 + ak + 4];
        float4 b0 = *(const float4*)&W[(size_t)(k0 + br) * 1024 + n0 + bn];
        float4 b1 = *(const float4*)&W[(size_t)(k0 + br) * 1024 + n0 + bn + 4];
        As[ak + 0][ar] = a0.x; As[ak + 1][ar] = a0.y;
        As[ak + 2][ar] = a0.z; As[ak + 3][ar] = a0.w;
        As[ak + 4][ar] = a1.x; As[ak + 5][ar] = a1.y;
        As[ak + 6][ar] = a1.z; As[ak + 7][ar] = a1.w;
        *(float4*)&Bs[br][bn]     = b0;
        *(float4*)&Bs[br][bn + 4] = b1;
        __syncthreads();
        #pragma unroll
        for (int kk = 0; kk < 16; ++kk) {
            float4 xa = *(const float4*)&As[kk][ty * 8];
            float4 xb = *(const float4*)&As[kk][ty * 8 + 4];
            float4 ya = *(const float4*)&Bs[kk][tx * 8];
            float4 yb = *(const float4*)&Bs[kk][tx * 8 + 4];
            float a[8] = {xa.x, xa.y, xa.z, xa.w, xb.x, xb.y, xb.z, xb.w};
            float b[8] = {ya.x, ya.y, ya.z, ya.w, yb.x, yb.y, yb.z, yb.w};
            #pragma unroll
            for (int i = 0; i < 8; ++i)
                #pragma unroll
                for (int j = 0; j < 8; ++j)
                    acc[i][j] += a[i] * b[j];
        }
    }
    #pragma unroll
    for (int i = 0; i < 8; ++i) {
        float4 r0, r1;
        r0.x = acc[i][0]; r0.y = acc[i][1]; r0.z = acc[i][2]; r0.w = acc[i][3];
        r1.x = acc[i][4]; r1.y = acc[i][5]; r1.z = acc[i][6]; r1.w = acc[i][7];
        float* op = &out[(size_t)(m0 + ty * 8 + i) * 1024 + n0 + tx * 8];
        *(float4*)op       = r0;
        *(float4*)(op + 4) = r1;
    }
}

// ---------------------------------------------------------------------------
// q, k, lambda projections.
// ---------------------------------------------------------------------------
__global__ __launch_bounds__(256) void qkl_kernel(const float* __restrict__ X,
    const float* __restrict__ Wq, const float* __restrict__ Wk,
    const float* __restrict__ Wd, const float* __restrict__ bd,
    float* __restrict__ q, float* __restrict__ k, float* __restrict__ lam)
{
    __shared__ float xs[8 * 512];
    const int tid = threadIdx.x;
    const size_t row0 = (size_t)blockIdx.x * 8;
    #pragma unroll
    for (int c = 0; c < 4; ++c) {
        int f = (c * 256 + tid) * 4;
        *(float4*)&xs[f] = *(const float4*)&X[row0 * 512 + f];
    }
    __syncthreads();
    for (int t = tid; t < 264; t += 256) {
        int r = t / 33, c = t - r * 33;
        const float* xr = &xs[r * 512];
        const float* Wp; int ldw;
        if (c < 16)      { Wp = Wq + c;        ldw = 16; }
        else if (c < 32) { Wp = Wk + (c - 16); ldw = 16; }
        else             { Wp = Wd;            ldw = 1;  }
        float s = 0.f;
        for (int kk = 0; kk < 512; ++kk) s += xr[kk] * Wp[(size_t)kk * ldw];
        if (c < 16)      q[(row0 + r) * 16 + c] = s;
        else if (c < 32) k[(row0 + r) * 16 + (c - 16)] = s;
        else             lam[row0 + r] = 1.f / (1.f + expf(-(s + bd[0])));
    }
}

// ---------------------------------------------------------------------------
// Fused recurrence — byte-identical to the R8-proven kernel (6.55 ms):
// XCD-local exchange groups, per-thread fast/slow scope select with sticky
// escalation, wave3 fused fast-weight scan, 4-wave matvec + butterfly,
// wave0 finisher. (R10's 128-reg weights spilled: keep 128 regs MAX state.)
// ---------------------------------------------------------------------------
__global__ __launch_bounds__(256, 1) void rec_fused(
    const float* __restrict__ Wh, const float* __restrict__ qg,
    const float* __restrict__ kg, const float* __restrict__ vg,
    const float* __restrict__ lamg, const float* __restrict__ bias,
    float* __restrict__ out0, float* __restrict__ hfin,
    float* __restrict__ Ffin, float* __restrict__ hbuf,
    int* __restrict__ xcc_tab)
{
    __shared__ float hs[2 * 1152];     // phys(b,k) = b*1152 + (k>>5)*36 + (k&31)
    __shared__ float red2[2][256];     // [buf][wave*64 + cu*8 + z]
    __shared__ float pre_lds[2][64];   // [buf][bb*32 + ci]
    __shared__ float F_lds[64][17];    // fast-weight state, pad 17

    const int tid = threadIdx.x;
    const int bid = blockIdx.x;
    const int g = bid & 7, sl = bid >> 3;
    const int c0 = sl * 32;
    const int kp = tid >> 3;          // k-part: 32 k's (kp*32 .. +31)
    const int cu = tid & 7;           // col unit: 4 cols (c0 + cu*4 + j)
    const int wv = tid >> 6;

    // ---- publish my XCD id (value xcc+1; table memset to 0xFF each launch)
    const int my_xcc = __builtin_amdgcn_s_getreg(63508) & 0xF; // hwreg XCC_ID
    if (tid == 0) {
        int val = my_xcc + 1;
        int* tp = xcc_tab + bid;
        asm volatile("global_store_dword %0, %1, off sc0 sc1"
                     :: "v"(tp), "v"(val) : "memory");
    }

    // ---- weights: 128 regs/thread, all indices compile-time
    float wr[128];
    #pragma unroll
    for (int i = 0; i < 32; ++i) {
        float4 w4 = *(const float4*)&Wh[(size_t)(kp * 32 + i) * 1024 + c0 + cu * 4];
        wr[i * 4 + 0] = w4.x; wr[i * 4 + 1] = w4.y;
        wr[i * 4 + 2] = w4.z; wr[i * 4 + 3] = w4.w;
    }

    // ---- stage/poll geometry: thread owns 8 h values of one batch
    const int sb_ = tid >> 7;                // batch-in-group 0/1
    const int f   = (tid & 127) * 8;         // col offset 0..1016
    float* stage_base = &hs[sb_ * 1152 + (f >> 5) * 36 + (f & 31)];

    // ---- scope detect: producer of my window
    int fastf;
    {
        const int prod_bid = (f >> 5) * 8 + g;
        const int* tp = xcc_tab + prod_bid;
        int tv;
        for (;;) {
            asm volatile("global_load_dword %0, %1, off sc0 sc1\n\t"
                         "s_waitcnt vmcnt(0)"
                         : "=&v"(tv) : "v"(tp) : "memory");
            if (tv != -1) break;
        }
        fastf = ((tv - 1) == my_xcc) ? 1 : 0;
    }

    // ---- roles
    const int j64 = tid & 63;
    const int fb = j64 >> 5, fci = j64 & 31;   // (batch-in-group, col-in-slice)
    const int bg = g * 2 + fb;                 // global batch
    const bool isScan = (tid >= 192);
    const bool isFin  = (tid < 64);

    float bias_r = 0.f, plam = 0.f, pv = 0.f, pxw = 0.f;
    float4 pq[4], pk4[4];
    if (isScan) {
        bias_r = bias[c0 + fci];
        #pragma unroll
        for (int r = 0; r < 16; ++r) F_lds[j64][r] = 0.f;
        const size_t row = (size_t)bg * Tc;             // t = 0 inputs
        plam = lamg[row];
        pv   = vg[row * Hc + c0 + fci];
        pxw  = out0[row * Hc + c0 + fci];
        const float* qp  = qg + row * 16;
        const float* kpp = kg + row * 16;
        #pragma unroll
        for (int r4 = 0; r4 < 4; ++r4) {
            pq[r4]  = *(const float4*)(qp + r4 * 4);
            pk4[r4] = *(const float4*)(kpp + r4 * 4);
        }
    }

    for (int t = 0; t < Tc; ++t) {
        const int buf = t & 1;
        float* h_rd = hbuf + (t & 1) * (16 * 1024) + g * 2048;
        float* h_wr = hbuf + ((t + 1) & 1) * (16 * 1024) + g * 2048;
        const float off_r = ((t >> 1) & 1) ? 4.0f : 0.0f;
        const float off_w = (((t + 1) >> 1) & 1) ? 4.0f : 0.0f;

        // ---- wave3: fast-weight scan (hidden under the poll) ----
        if (isScan) {
            float rd = 0.f;
            #pragma unroll
            for (int r4 = 0; r4 < 4; ++r4) {
                float f0 = F_lds[j64][r4 * 4 + 0];
                float f1 = F_lds[j64][r4 * 4 + 1];
                float f2 = F_lds[j64][r4 * 4 + 2];
                float f3 = F_lds[j64][r4 * 4 + 3];
                f0 = plam * f0 + pv * pk4[r4].x; rd += f0 * pq[r4].x;
                f1 = plam * f1 + pv * pk4[r4].y; rd += f1 * pq[r4].y;
                f2 = plam * f2 + pv * pk4[r4].z; rd += f2 * pq[r4].z;
                f3 = plam * f3 + pv * pk4[r4].w; rd += f3 * pq[r4].w;
                F_lds[j64][r4 * 4 + 0] = f0;
                F_lds[j64][r4 * 4 + 1] = f1;
                F_lds[j64][r4 * 4 + 2] = f2;
                F_lds[j64][r4 * 4 + 3] = f3;
            }
            pre_lds[buf][j64] = pxw + rd + bias_r;
            if (t == Tc - 1) {
                #pragma unroll
                for (int r = 0; r < 16; ++r)
                    Ffin[((size_t)bg * Hc + c0 + fci) * 16 + r] = F_lds[j64][r];
            } else {
                const size_t row = (size_t)bg * Tc + (t + 1);
                plam = lamg[row];
                pv   = vg[row * Hc + c0 + fci];
                pxw  = out0[row * Hc + c0 + fci];
                const float* qp  = qg + row * 16;
                const float* kpp = kg + row * 16;
                #pragma unroll
                for (int r4 = 0; r4 < 4; ++r4) {
                    pq[r4]  = *(const float4*)(qp + r4 * 4);
                    pk4[r4] = *(const float4*)(kpp + r4 * 4);
                }
            }
        }

        // ---- poll own 8-value window, stage into hs ----
        if (t > 0) {
            const float lo = off_r - 1.5f, hi = off_r + 1.5f;
            const float* p0 = h_rd + sb_ * 1024 + f;
            const float* p1 = p0 + 4;
            float4 r0, r1;
            int tries = 0;
            for (;;) {
                if (fastf) {
                    asm volatile(
                        "global_load_dwordx4 %0, %2, off sc0\n\t"
                        "global_load_dwordx4 %1, %3, off sc0\n\t"
                        "s_waitcnt vmcnt(0)"
                        : "=&v"(r0), "=&v"(r1)
                        : "v"(p0), "v"(p1) : "memory");
                } else {
                    asm volatile(
                        "global_load_dwordx4 %0, %2, off sc0 sc1\n\t"
                        "global_load_dwordx4 %1, %3, off sc0 sc1\n\t"
                        "s_waitcnt vmcnt(0)"
                        : "=&v"(r0), "=&v"(r1)
                        : "v"(p0), "v"(p1) : "memory");
                }
                bool ok = r0.x > lo && r0.x < hi && r0.y > lo && r0.y < hi
                       && r0.z > lo && r0.z < hi && r0.w > lo && r0.w < hi
                       && r1.x > lo && r1.x < hi && r1.y > lo && r1.y < hi
                       && r1.z > lo && r1.z < hi && r1.w > lo && r1.w < hi;
                if (ok) break;
                if (fastf && ++tries > 64) fastf = 0;  // sticky escalation
            }
            r0.x -= off_r; r0.y -= off_r; r0.z -= off_r; r0.w -= off_r;
            r1.x -= off_r; r1.y -= off_r; r1.z -= off_r; r1.w -= off_r;
            *(float4*)(stage_base)     = r0;
            *(float4*)(stage_base + 4) = r1;
        } else {
            float4 z = {0.f, 0.f, 0.f, 0.f};
            *(float4*)(stage_base)     = z;
            *(float4*)(stage_base + 4) = z;
        }
        __syncthreads();                       // B: hs ready

        // ---- matvec: 16 b128 LDS reads, 256 FMAs per thread ----
        float acc[8];
        #pragma unroll
        for (int z = 0; z < 8; ++z) acc[z] = 0.f;
        #pragma unroll
        for (int bb = 0; bb < 2; ++bb) {
            const float* hb = &hs[bb * 1152 + kp * 36];
            #pragma unroll
            for (int i = 0; i < 8; ++i) {
                float4 h4 = *(const float4*)(hb + i * 4);
                #pragma unroll
                for (int j = 0; j < 4; ++j)
                    acc[j * 2 + bb] += h4.x * wr[(i * 4 + 0) * 4 + j]
                                     + h4.y * wr[(i * 4 + 1) * 4 + j]
                                     + h4.z * wr[(i * 4 + 2) * 4 + j]
                                     + h4.w * wr[(i * 4 + 3) * 4 + j];
            }
        }

        // ---- butterfly over the wave's 8 k-parts (lane bits 3,4,5) ----
        #pragma unroll
        for (int z = 0; z < 8; ++z) {
            float s = acc[z];
            s += __shfl_xor(s, 8);
            s += __shfl_xor(s, 16);
            s += __shfl_xor(s, 32);
            acc[z] = s;
        }
        if (j64 < 8) {                          // one lane per cu
            float4 ra, rb;
            ra.x = acc[0]; ra.y = acc[1]; ra.z = acc[2]; ra.w = acc[3];
            rb.x = acc[4]; rb.y = acc[5]; rb.z = acc[6]; rb.w = acc[7];
            *(float4*)&red2[buf][wv * 64 + j64 * 8]     = ra;
            *(float4*)&red2[buf][wv * 64 + j64 * 8 + 4] = rb;
        }
        __syncthreads();                       // C: red2 + pre_lds ready

        // ---- finisher: combine 4 wave-partials, tanh, store ----
        if (isFin) {
            const int cu_f = fci >> 2, jf = fci & 3;
            const int z = jf * 2 + fb;
            float tot = pre_lds[buf][j64];
            #pragma unroll
            for (int ww = 0; ww < 4; ++ww)
                tot += red2[buf][ww * 64 + cu_f * 8 + z];
            float hv = tanhf(tot);
            float sv = hv + off_w;             // self-signaling store first
            float* hp = h_wr + fb * 1024 + c0 + fci;
            asm volatile(
                "global_store_dword %0, %1, off sc0 sc1"
                :: "v"(hp), "v"(sv) : "memory");
            size_t oidx = ((size_t)bg * Tc + t) * Hc + c0 + fci;
            out0[oidx] = hv;
            if (t == Tc - 1) hfin[(size_t)bg * Hc + c0 + fci] = hv;
        }
    }
}

// ---------------------------------------------------------------------------
extern "C" void kernel_launch(void* const* d_in, const int* in_sizes, int n_in,
                              void* d_out, int out_size, void* d_ws, size_t ws_size,
                              hipStream_t stream)
{
    const float* x    = (const float*)d_in[0];
    const float* Wx   = (const float*)d_in[1];
    const float* Wh   = (const float*)d_in[2];
    const float* Wq   = (const float*)d_in[3];
    const float* Wk   = (const float*)d_in[4];
    const float* Wv   = (const float*)d_in[5];
    const float* Wd   = (const float*)d_in[6];
    const float* bias = (const float*)d_in[7];
    const float* bd   = (const float*)d_in[8];

    float* out0 = (float*)d_out;                    // (B,T,H): xw, then h
    float* hfin = out0 + (size_t)Bc * Tc * Hc;      // (B,H)
    float* Ffin = hfin + (size_t)Bc * Hc;           // (B,H,R)

    float* wsf  = (float*)d_ws;
    float* v    = wsf;                               // B*T*H
    float* q    = v + (size_t)Bc * Tc * Hc;          // B*T*R
    float* k    = q + (size_t)Bc * Tc * Rc;          // B*T*R
    float* lam  = k + (size_t)Bc * Tc * Rc;          // B*T
    float* hbuf = lam + (size_t)Bc * Tc;             // 2 * B*H ping-pong
    int*   xcc  = (int*)(hbuf + 2 * (size_t)Bc * Hc);// 256 entries

    // 0x7F7F7F7F == 3.39e38f: invalid under both offsets -> poll-safe init.
    hipMemsetAsync(hbuf, 0x7F, 2 * (size_t)Bc * Hc * sizeof(float), stream);
    hipMemsetAsync(xcc, 0xFF, 256 * sizeof(int), stream);

    dim3 gp(256, 8, 2);
    gemm_fused<<<gp, 256, 0, stream>>>(x, Wx, Wv, out0, v);
    qkl_kernel<<<4096, 256, 0, stream>>>(x, Wq, Wk, Wd, bd, q, k, lam);
    rec_fused<<<256, 256, 0, stream>>>(Wh, q, k, v, lam, bias,
                                       out0, hfin, Ffin, hbuf, xcc);
}